// Round 1
// baseline (609.742 us; speedup 1.0000x reference)
//
#include <hip/hip_runtime.h>

#define NUSERS 100000
#define NBOOKS 50000
#define NNODES 150000
#define HID 128
#define FEAT 256
#define EPR 500000   // edges per relation

// ---------------------------------------------------------------------------
// GEMM: C[m][h] = (sum_k X[m][k]*W[h][k] + b[h]) * scale
// X: M x 256 row-major, W: 128 x 256 row-major (so both K-contiguous).
// Block 256 threads, tile BM=64 x BN=128, BK=32. Each thread: 8 rows x 4 cols.
// ---------------------------------------------------------------------------
__global__ __launch_bounds__(256) void gemm_xwT(
    const float* __restrict__ X, const float* __restrict__ W,
    const float* __restrict__ b, float* __restrict__ C,
    int M, float scale)
{
  __shared__ float Xs[64][36];   // pad 36 -> 16B-aligned rows, few conflicts
  __shared__ float Ws[128][36];
  const int tid = threadIdx.x;
  const int tx  = tid & 31;      // col group: cols tx + j*32
  const int ty  = tid >> 5;      // row group: rows ty + i*8
  const int bm  = blockIdx.x * 64;

  float acc[8][4];
#pragma unroll
  for (int i = 0; i < 8; ++i)
#pragma unroll
    for (int j = 0; j < 4; ++j) acc[i][j] = 0.f;

  for (int step = 0; step < 8; ++step) {
    const int k0 = step * 32;
    __syncthreads();
    // X tile: 64x32 floats = 512 float4, 2 per thread
#pragma unroll
    for (int l = 0; l < 2; ++l) {
      int idx = tid + l * 256;
      int row = idx >> 3, c4 = idx & 7;
      int gr = bm + row;
      float4 v = make_float4(0.f, 0.f, 0.f, 0.f);
      if (gr < M) v = *reinterpret_cast<const float4*>(&X[(size_t)gr * FEAT + k0 + c4 * 4]);
      *reinterpret_cast<float4*>(&Xs[row][c4 * 4]) = v;
    }
    // W tile: 128x32 floats = 1024 float4, 4 per thread
#pragma unroll
    for (int l = 0; l < 4; ++l) {
      int idx = tid + l * 256;
      int row = idx >> 3, c4 = idx & 7;
      float4 v = *reinterpret_cast<const float4*>(&W[(size_t)row * FEAT + k0 + c4 * 4]);
      *reinterpret_cast<float4*>(&Ws[row][c4 * 4]) = v;
    }
    __syncthreads();
#pragma unroll
    for (int kk = 0; kk < 32; kk += 4) {
      float4 xv[8], wv[4];
#pragma unroll
      for (int i = 0; i < 8; ++i)
        xv[i] = *reinterpret_cast<const float4*>(&Xs[ty + i * 8][kk]);
#pragma unroll
      for (int j = 0; j < 4; ++j)
        wv[j] = *reinterpret_cast<const float4*>(&Ws[tx + j * 32][kk]);
#pragma unroll
      for (int i = 0; i < 8; ++i)
#pragma unroll
        for (int j = 0; j < 4; ++j) {
          acc[i][j] += xv[i].x * wv[j].x;
          acc[i][j] += xv[i].y * wv[j].y;
          acc[i][j] += xv[i].z * wv[j].z;
          acc[i][j] += xv[i].w * wv[j].w;
        }
    }
  }
#pragma unroll
  for (int j = 0; j < 4; ++j) {
    int col = tx + j * 32;
    float bj = b[col];
#pragma unroll
    for (int i = 0; i < 8; ++i) {
      int gr = bm + ty + i * 8;
      if (gr < M) C[(size_t)gr * HID + col] = (acc[i][j] + bj) * scale;
    }
  }
}

// ---------------------------------------------------------------------------
// Edge decode: thread i in [0, 2*EPR) handles one original edge (rates then
// implicit). It contributes BOTH directions:
//   forward:  row = u,           col = bk      (raw book id, per reference!)
//   reverse:  row = NUSERS + bk, col = u
// ---------------------------------------------------------------------------
__device__ __forceinline__ void decode_edge(const int* __restrict__ rates,
                                            const int* __restrict__ impl,
                                            int i, int& u, int& bk)
{
  if (i < EPR) { u = rates[i]; bk = rates[EPR + i]; }
  else { int j = i - EPR; u = impl[j]; bk = impl[EPR + j]; }
}

__global__ void deg_kernel(const int* __restrict__ rates, const int* __restrict__ impl,
                           int* __restrict__ deg)
{
  int i = blockIdx.x * blockDim.x + threadIdx.x;
  if (i >= 2 * EPR) return;
  int u, bk;
  decode_edge(rates, impl, i, u, bk);
  atomicAdd(&deg[bk], 1);   // forward edge's col
  atomicAdd(&deg[u], 1);    // reverse edge's col
}

__global__ void dis_kernel(const int* __restrict__ deg, float* __restrict__ dis, int n)
{
  int i = blockIdx.x * blockDim.x + threadIdx.x;
  if (i < n) {
    int d = deg[i];
    dis[i] = (d > 0) ? rsqrtf((float)d) : 0.f;
  }
}

__global__ void count_kernel(const int* __restrict__ rates, const int* __restrict__ impl,
                             const float* __restrict__ dis, int* __restrict__ counts)
{
  int i = blockIdx.x * blockDim.x + threadIdx.x;
  if (i >= 2 * EPR) return;
  int u, bk;
  decode_edge(rates, impl, i, u, bk);
  float du = dis[u], db = dis[bk], dr = dis[NUSERS + bk];
  float nf = du * db;   // forward norm
  float nr = dr * du;   // reverse norm (structurally 0, but keep general)
  if (nf != 0.f) atomicAdd(&counts[bk], 1);
  if (nr != 0.f) atomicAdd(&counts[u], 1);
}

__global__ void fill_kernel(const int* __restrict__ rates, const int* __restrict__ impl,
                            const float* __restrict__ dis, int* __restrict__ cur,
                            int* __restrict__ brow, float* __restrict__ bnorm)
{
  int i = blockIdx.x * blockDim.x + threadIdx.x;
  if (i >= 2 * EPR) return;
  int u, bk;
  decode_edge(rates, impl, i, u, bk);
  float du = dis[u], db = dis[bk], dr = dis[NUSERS + bk];
  float nf = du * db;
  float nr = dr * du;
  if (nf != 0.f) { int pos = atomicAdd(&cur[bk], 1); brow[pos] = u; bnorm[pos] = nf; }
  if (nr != 0.f) { int pos = atomicAdd(&cur[u], 1);  brow[pos] = NUSERS + bk; bnorm[pos] = nr; }
}

// ---------------------------------------------------------------------------
// 3-phase exclusive scan of counts[0..N) -> offs[0..N]
// ---------------------------------------------------------------------------
__global__ __launch_bounds__(1024) void scan_blocks(const int* __restrict__ counts,
                                                    int* __restrict__ offs,
                                                    int* __restrict__ bsum, int N)
{
  __shared__ int buf[1024];
  int t = threadIdx.x;
  int i = blockIdx.x * 1024 + t;
  int v = (i < N) ? counts[i] : 0;
  buf[t] = v;
  __syncthreads();
  for (int off = 1; off < 1024; off <<= 1) {
    int x = (t >= off) ? buf[t - off] : 0;
    __syncthreads();
    buf[t] += x;
    __syncthreads();
  }
  int incl = buf[t];
  if (i < N) offs[i] = incl - v;           // block-local exclusive
  if (t == 1023) bsum[blockIdx.x] = incl;  // block total
}

__global__ void scan_totals(const int* __restrict__ bsum, int* __restrict__ bpre,
                            int* __restrict__ offs, int nb, int N)
{
  if (threadIdx.x == 0 && blockIdx.x == 0) {
    int run = 0;
    for (int b = 0; b < nb; ++b) { bpre[b] = run; run += bsum[b]; }
    offs[N] = run;
  }
}

__global__ void add_prefix(int* __restrict__ offs, const int* __restrict__ bpre, int N)
{
  int i = blockIdx.x * blockDim.x + threadIdx.x;
  if (i < N) offs[i] += bpre[i >> 10];
}

// ---------------------------------------------------------------------------
// Pull aggregation: one block (128 threads = one feature each) per dest node.
// ---------------------------------------------------------------------------
__global__ __launch_bounds__(128) void pull1(const float* __restrict__ src,
    const int* __restrict__ offs, const int* __restrict__ brow,
    const float* __restrict__ bnorm, float* __restrict__ dst)
{
  const int c = blockIdx.x;
  const int f = threadIdx.x;
  int s = offs[c], e = offs[c + 1];
  float acc = 0.f;
  int i = s;
  for (; i + 4 <= e; i += 4) {
    int   r0 = brow[i],     r1 = brow[i + 1], r2 = brow[i + 2], r3 = brow[i + 3];
    float w0 = bnorm[i],    w1 = bnorm[i + 1], w2 = bnorm[i + 2], w3 = bnorm[i + 3];
    acc += w0 * src[(size_t)r0 * HID + f];
    acc += w1 * src[(size_t)r1 * HID + f];
    acc += w2 * src[(size_t)r2 * HID + f];
    acc += w3 * src[(size_t)r3 * HID + f];
  }
  for (; i < e; ++i) acc += bnorm[i] * src[(size_t)brow[i] * HID + f];
  dst[(size_t)c * HID + f] = acc;
}

__global__ __launch_bounds__(128) void pull2_final(const float* __restrict__ h1,
    const int* __restrict__ offs, const int* __restrict__ brow,
    const float* __restrict__ bnorm, const float* __restrict__ cu0,
    float* __restrict__ outu)
{
  const int c = blockIdx.x;
  const int f = threadIdx.x;
  int s = offs[c], e = offs[c + 1];
  float acc = 0.f;
  int i = s;
  for (; i + 4 <= e; i += 4) {
    int   r0 = brow[i],     r1 = brow[i + 1], r2 = brow[i + 2], r3 = brow[i + 3];
    float w0 = bnorm[i],    w1 = bnorm[i + 1], w2 = bnorm[i + 2], w3 = bnorm[i + 3];
    acc += w0 * h1[(size_t)r0 * HID + f];
    acc += w1 * h1[(size_t)r1 * HID + f];
    acc += w2 * h1[(size_t)r2 * HID + f];
    acc += w3 * h1[(size_t)r3 * HID + f];
  }
  for (; i < e; ++i) acc += bnorm[i] * h1[(size_t)brow[i] * HID + f];
  size_t idx = (size_t)c * HID + f;
  outu[idx] = (cu0[idx] + h1[idx] + acc) * (1.0f / 3.0f);
}

// ---------------------------------------------------------------------------
extern "C" void kernel_launch(void* const* d_in, const int* in_sizes, int n_in,
                              void* d_out, int out_size, void* d_ws, size_t ws_size,
                              hipStream_t stream)
{
  const float* user_x = (const float*)d_in[0];
  const float* book_x = (const float*)d_in[1];
  const float* user_W = (const float*)d_in[2];
  const float* user_b = (const float*)d_in[3];
  const float* book_W = (const float*)d_in[4];
  const float* book_b = (const float*)d_in[5];
  const int*   rates  = (const int*)d_in[6];
  const int*   impl   = (const int*)d_in[7];

  float* out      = (float*)d_out;
  float* out_user = out;                         // 100000 x 128
  float* out_book = out + (size_t)NUSERS * HID;  // 50000 x 128

  // carve workspace (~120 MB)
  char* p = (char*)d_ws;
  auto carve = [&](size_t bytes) -> void* {
    void* r = (void*)p;
    p += (bytes + 255) & ~(size_t)255;
    return r;
  };
  float* cu0    = (float*)carve((size_t)NUSERS * HID * 4);
  float* h1     = (float*)carve((size_t)NUSERS * HID * 4);
  int*   degi   = (int*)carve((size_t)NNODES * 4);
  float* dis    = (float*)carve((size_t)NNODES * 4);
  int*   counts = (int*)carve((size_t)(NUSERS + 2) * 4);
  int*   offs   = (int*)carve((size_t)(NUSERS + 2) * 4);
  int*   bsum   = (int*)carve(256 * 4);
  int*   bpre   = (int*)carve(256 * 4);
  int*   cur    = (int*)carve((size_t)NUSERS * 4);
  int*   brow   = (int*)carve((size_t)4 * EPR * 4);
  float* bnorm  = (float*)carve((size_t)4 * EPR * 4);

  hipMemsetAsync(degi, 0, (size_t)NNODES * 4, stream);
  hipMemsetAsync(counts, 0, (size_t)(NUSERS + 2) * 4, stream);

  // linear transforms
  gemm_xwT<<<(NUSERS + 63) / 64, 256, 0, stream>>>(user_x, user_W, user_b, cu0, NUSERS, 1.0f);
  gemm_xwT<<<(NBOOKS + 63) / 64, 256, 0, stream>>>(book_x, book_W, book_b, out_book, NBOOKS, 1.0f / 3.0f);

  // degree / norm
  const int nthr = 2 * EPR;
  deg_kernel<<<(nthr + 255) / 256, 256, 0, stream>>>(rates, impl, degi);
  dis_kernel<<<(NNODES + 255) / 256, 256, 0, stream>>>(degi, dis, NNODES);

  // CSR build (nonzero-norm edges only)
  count_kernel<<<(nthr + 255) / 256, 256, 0, stream>>>(rates, impl, dis, counts);
  const int nb = (NUSERS + 1023) / 1024;  // 98
  scan_blocks<<<nb, 1024, 0, stream>>>(counts, offs, bsum, NUSERS);
  scan_totals<<<1, 64, 0, stream>>>(bsum, bpre, offs, nb, NUSERS);
  add_prefix<<<(NUSERS + 255) / 256, 256, 0, stream>>>(offs, bpre, NUSERS);
  hipMemcpyAsync(cur, offs, (size_t)NUSERS * 4, hipMemcpyDeviceToDevice, stream);
  fill_kernel<<<(nthr + 255) / 256, 256, 0, stream>>>(rates, impl, dis, cur, brow, bnorm);

  // propagation layers (pull mode), layer 2 fuses final mean epilogue
  pull1<<<NUSERS, 128, 0, stream>>>(cu0, offs, brow, bnorm, h1);
  pull2_final<<<NUSERS, 128, 0, stream>>>(h1, offs, brow, bnorm, cu0, out_user);
}

// Round 2
// 468.245 us; speedup vs baseline: 1.3022x; 1.3022x over previous
//
#include <hip/hip_runtime.h>

#define NUSERS 100000
#define NBOOKS 50000
#define HID 128
#define FEAT 256
#define EPR 500000   // edges per relation; 1M original edges total

typedef __attribute__((ext_vector_type(8))) short bf16x8;
typedef __attribute__((ext_vector_type(4))) float f32x4;

__device__ __forceinline__ unsigned short f2bf(float f) {
  union { float f; unsigned u; } v; v.f = f;
  unsigned r = v.u + 0x7FFFu + ((v.u >> 16) & 1u);   // round-nearest-even
  return (unsigned short)(r >> 16);
}
__device__ __forceinline__ float bf2f(unsigned short h) {
  union { unsigned u; float f; } v; v.u = ((unsigned)h) << 16;
  return v.f;
}

// ---------------------------------------------------------------------------
// Cast both weight matrices (128x256) to bf16. Tiny.
// ---------------------------------------------------------------------------
__global__ void cast_w(const float* __restrict__ w0, const float* __restrict__ w1,
                       unsigned short* __restrict__ o0, unsigned short* __restrict__ o1)
{
  int i = blockIdx.x * 256 + threadIdx.x;
  if (i < HID * FEAT) { o0[i] = f2bf(w0[i]); o1[i] = f2bf(w1[i]); }
}

// ---------------------------------------------------------------------------
// bf16 MFMA GEMM, direct-from-global (no LDS): C = (X @ W^T + b) * scale.
// X fp32 (M x 256) converted to bf16 in-register; Wb bf16 (128 x 256).
// Block 256 thr = 4 waves, 2x2 wave grid, each wave 64x64 out (4x4 16x16 frags).
// mfma_f32_16x16x32_bf16: A lane l: row=l&15, k=(l>>4)*8+j (16B contiguous)
//                         B lane l: col=l&15, k=(l>>4)*8+j (16B contiguous)
//                         D lane l: col=l&15, row=(l>>4)*4+j
// Optionally writes a bf16 shadow copy Cb for downstream gathers.
// ---------------------------------------------------------------------------
__global__ __launch_bounds__(256) void gemm_mfma(
    const float* __restrict__ X, const unsigned short* __restrict__ Wb,
    const float* __restrict__ bias, float* __restrict__ C,
    unsigned short* __restrict__ Cb, int M, float scale)
{
  const int tid  = threadIdx.x;
  const int lane = tid & 63;
  const int w    = tid >> 6;
  const int wm   = w & 1, wn = w >> 1;
  const int bm   = blockIdx.x * 128;
  const int l15  = lane & 15;
  const int l4   = lane >> 4;

  f32x4 acc[4][4];
#pragma unroll
  for (int i = 0; i < 4; ++i)
#pragma unroll
    for (int j = 0; j < 4; ++j) acc[i][j] = (f32x4)0.f;

  int rrow[4]; bool rok[4];
#pragma unroll
  for (int mi = 0; mi < 4; ++mi) {
    rrow[mi] = bm + wm * 64 + mi * 16 + l15;
    rok[mi]  = rrow[mi] < M;
  }

  for (int ks = 0; ks < 8; ++ks) {
    const int k0 = ks * 32 + l4 * 8;
    bf16x8 a[4], b[4];
#pragma unroll
    for (int ni = 0; ni < 4; ++ni) {
      int col = wn * 64 + ni * 16 + l15;
      b[ni] = *reinterpret_cast<const bf16x8*>(&Wb[(size_t)col * FEAT + k0]);
    }
#pragma unroll
    for (int mi = 0; mi < 4; ++mi) {
      if (rok[mi]) {
        const float4* ap = reinterpret_cast<const float4*>(&X[(size_t)rrow[mi] * FEAT + k0]);
        float4 x0 = ap[0], x1 = ap[1];
        bf16x8 av;
        av[0] = (short)f2bf(x0.x); av[1] = (short)f2bf(x0.y);
        av[2] = (short)f2bf(x0.z); av[3] = (short)f2bf(x0.w);
        av[4] = (short)f2bf(x1.x); av[5] = (short)f2bf(x1.y);
        av[6] = (short)f2bf(x1.z); av[7] = (short)f2bf(x1.w);
        a[mi] = av;
      } else {
        a[mi] = (bf16x8)(short)0;
      }
    }
#pragma unroll
    for (int mi = 0; mi < 4; ++mi)
#pragma unroll
      for (int ni = 0; ni < 4; ++ni)
        acc[mi][ni] = __builtin_amdgcn_mfma_f32_16x16x32_bf16(a[mi], b[ni], acc[mi][ni], 0, 0, 0);
  }

#pragma unroll
  for (int ni = 0; ni < 4; ++ni) {
    int col = wn * 64 + ni * 16 + l15;
    float bj = bias[col];
#pragma unroll
    for (int mi = 0; mi < 4; ++mi) {
#pragma unroll
      for (int j = 0; j < 4; ++j) {
        int r = bm + wm * 64 + mi * 16 + l4 * 4 + j;
        if (r < M) {
          float vv = (acc[mi][ni][j] + bj) * scale;
          C[(size_t)r * HID + col] = vv;
          if (Cb) Cb[(size_t)r * HID + col] = f2bf(vv);
        }
      }
    }
  }
}

// ---------------------------------------------------------------------------
// Graph preprocessing. Only forward edges (row=u, col=bk) can have nonzero
// norm: reverse edges' source nodes (NUSERS+bk) never appear as col -> deg 0
// -> dis 0 -> norm 0. deg still counts BOTH directions' cols (bk and u).
// ---------------------------------------------------------------------------
__device__ __forceinline__ void decode_edge(const int* __restrict__ rates,
                                            const int* __restrict__ impl,
                                            int i, int& u, int& bk)
{
  if (i < EPR) { u = rates[i]; bk = rates[EPR + i]; }
  else { int j = i - EPR; u = impl[j]; bk = impl[EPR + j]; }
}

__global__ void deg_kernel(const int* __restrict__ rates, const int* __restrict__ impl,
                           int* __restrict__ deg)
{
  int i = blockIdx.x * blockDim.x + threadIdx.x;
  if (i >= 2 * EPR) return;
  int u, bk;
  decode_edge(rates, impl, i, u, bk);
  atomicAdd(&deg[bk], 1);   // forward edge's col
  atomicAdd(&deg[u], 1);    // reverse edge's col
}

__global__ void dis_kernel(const int* __restrict__ deg, float* __restrict__ dis, int n)
{
  int i = blockIdx.x * blockDim.x + threadIdx.x;
  if (i < n) {
    int d = deg[i];
    dis[i] = (d > 0) ? rsqrtf((float)d) : 0.f;
  }
}

__global__ void count_kernel(const int* __restrict__ rates, const int* __restrict__ impl,
                             const float* __restrict__ dis, int* __restrict__ counts)
{
  int i = blockIdx.x * blockDim.x + threadIdx.x;
  if (i >= 2 * EPR) return;
  int u, bk;
  decode_edge(rates, impl, i, u, bk);
  float nf = dis[u] * dis[bk];
  if (nf != 0.f) atomicAdd(&counts[bk], 1);
}

__global__ void fill_kernel(const int* __restrict__ rates, const int* __restrict__ impl,
                            const float* __restrict__ dis, int* __restrict__ cur,
                            int* __restrict__ brow, float* __restrict__ bnorm)
{
  int i = blockIdx.x * blockDim.x + threadIdx.x;
  if (i >= 2 * EPR) return;
  int u, bk;
  decode_edge(rates, impl, i, u, bk);
  float nf = dis[u] * dis[bk];
  if (nf != 0.f) { int pos = atomicAdd(&cur[bk], 1); brow[pos] = u; bnorm[pos] = nf; }
}

// ---------------------------------------------------------------------------
// Exclusive scan of counts[0..N) -> offs[0..N]
// ---------------------------------------------------------------------------
__global__ __launch_bounds__(1024) void scan_blocks(const int* __restrict__ counts,
                                                    int* __restrict__ offs,
                                                    int* __restrict__ bsum, int N)
{
  __shared__ int buf[1024];
  int t = threadIdx.x;
  int i = blockIdx.x * 1024 + t;
  int v = (i < N) ? counts[i] : 0;
  buf[t] = v;
  __syncthreads();
  for (int off = 1; off < 1024; off <<= 1) {
    int x = (t >= off) ? buf[t - off] : 0;
    __syncthreads();
    buf[t] += x;
    __syncthreads();
  }
  int incl = buf[t];
  if (i < N) offs[i] = incl - v;
  if (t == 1023) bsum[blockIdx.x] = incl;
}

__global__ void scan_totals(const int* __restrict__ bsum, int* __restrict__ bpre,
                            int* __restrict__ offs, int nb, int N)
{
  if (threadIdx.x == 0 && blockIdx.x == 0) {
    int run = 0;
    for (int b = 0; b < nb; ++b) { bpre[b] = run; run += bsum[b]; }
    offs[N] = run;
  }
}

__global__ void add_prefix(int* __restrict__ offs, const int* __restrict__ bpre, int N)
{
  int i = blockIdx.x * blockDim.x + threadIdx.x;
  if (i < N) offs[i] += bpre[i >> 10];
}

// ---------------------------------------------------------------------------
// Pull aggregation over bf16 source rows. One block (128 thr) per dest node.
// ---------------------------------------------------------------------------
__global__ __launch_bounds__(128) void pull1(const unsigned short* __restrict__ srcb,
    const int* __restrict__ offs, const int* __restrict__ brow,
    const float* __restrict__ bnorm, float* __restrict__ dst,
    unsigned short* __restrict__ dstb)
{
  const int c = blockIdx.x;
  const int f = threadIdx.x;
  int s = offs[c], e = offs[c + 1];
  float acc = 0.f;
  int i = s;
  for (; i + 4 <= e; i += 4) {
    int   r0 = brow[i],  r1 = brow[i + 1], r2 = brow[i + 2], r3 = brow[i + 3];
    float w0 = bnorm[i], w1 = bnorm[i + 1], w2 = bnorm[i + 2], w3 = bnorm[i + 3];
    acc += w0 * bf2f(srcb[(size_t)r0 * HID + f]);
    acc += w1 * bf2f(srcb[(size_t)r1 * HID + f]);
    acc += w2 * bf2f(srcb[(size_t)r2 * HID + f]);
    acc += w3 * bf2f(srcb[(size_t)r3 * HID + f]);
  }
  for (; i < e; ++i) acc += bnorm[i] * bf2f(srcb[(size_t)brow[i] * HID + f]);
  size_t idx = (size_t)c * HID + f;
  dst[idx]  = acc;
  dstb[idx] = f2bf(acc);
}

__global__ __launch_bounds__(128) void pull2_final(const unsigned short* __restrict__ h1b,
    const int* __restrict__ offs, const int* __restrict__ brow,
    const float* __restrict__ bnorm, const float* __restrict__ cu0,
    const float* __restrict__ h1, float* __restrict__ outu)
{
  const int c = blockIdx.x;
  const int f = threadIdx.x;
  int s = offs[c], e = offs[c + 1];
  float acc = 0.f;
  int i = s;
  for (; i + 4 <= e; i += 4) {
    int   r0 = brow[i],  r1 = brow[i + 1], r2 = brow[i + 2], r3 = brow[i + 3];
    float w0 = bnorm[i], w1 = bnorm[i + 1], w2 = bnorm[i + 2], w3 = bnorm[i + 3];
    acc += w0 * bf2f(h1b[(size_t)r0 * HID + f]);
    acc += w1 * bf2f(h1b[(size_t)r1 * HID + f]);
    acc += w2 * bf2f(h1b[(size_t)r2 * HID + f]);
    acc += w3 * bf2f(h1b[(size_t)r3 * HID + f]);
  }
  for (; i < e; ++i) acc += bnorm[i] * bf2f(h1b[(size_t)brow[i] * HID + f]);
  size_t idx = (size_t)c * HID + f;
  outu[idx] = (cu0[idx] + h1[idx] + acc) * (1.0f / 3.0f);
}

// Users [NBOOKS, NUSERS) receive no messages: out = cu0/3; also zero h1b rows
// so pull2's gathers of those rows read 0.
__global__ __launch_bounds__(128) void upper_users(const float* __restrict__ cu0,
    unsigned short* __restrict__ h1b, float* __restrict__ outu)
{
  int c = NBOOKS + blockIdx.x;
  int f = threadIdx.x;
  size_t idx = (size_t)c * HID + f;
  h1b[idx] = 0;
  outu[idx] = cu0[idx] * (1.0f / 3.0f);
}

// ---------------------------------------------------------------------------
extern "C" void kernel_launch(void* const* d_in, const int* in_sizes, int n_in,
                              void* d_out, int out_size, void* d_ws, size_t ws_size,
                              hipStream_t stream)
{
  const float* user_x = (const float*)d_in[0];
  const float* book_x = (const float*)d_in[1];
  const float* user_W = (const float*)d_in[2];
  const float* user_b = (const float*)d_in[3];
  const float* book_W = (const float*)d_in[4];
  const float* book_b = (const float*)d_in[5];
  const int*   rates  = (const int*)d_in[6];
  const int*   impl   = (const int*)d_in[7];

  float* out      = (float*)d_out;
  float* out_user = out;
  float* out_book = out + (size_t)NUSERS * HID;

  char* p = (char*)d_ws;
  auto carve = [&](size_t bytes) -> void* {
    void* r = (void*)p;
    p += (bytes + 255) & ~(size_t)255;
    return r;
  };
  float*          cu0   = (float*)carve((size_t)NUSERS * HID * 4);
  unsigned short* cu0b  = (unsigned short*)carve((size_t)NUSERS * HID * 2);
  float*          h1    = (float*)carve((size_t)NBOOKS * HID * 4);   // only dests < NBOOKS
  unsigned short* h1b   = (unsigned short*)carve((size_t)NUSERS * HID * 2);
  unsigned short* wub   = (unsigned short*)carve((size_t)HID * FEAT * 2);
  unsigned short* wbb   = (unsigned short*)carve((size_t)HID * FEAT * 2);
  int*   degi   = (int*)carve((size_t)NUSERS * 4);
  float* dis    = (float*)carve((size_t)NUSERS * 4);
  int*   counts = (int*)carve((size_t)(NBOOKS + 2) * 4);
  int*   offs   = (int*)carve((size_t)(NBOOKS + 2) * 4);
  int*   bsum   = (int*)carve(256 * 4);
  int*   bpre   = (int*)carve(256 * 4);
  int*   cur    = (int*)carve((size_t)NBOOKS * 4);
  int*   brow   = (int*)carve((size_t)2 * EPR * 4);
  float* bnorm  = (float*)carve((size_t)2 * EPR * 4);

  hipMemsetAsync(degi, 0, (size_t)NUSERS * 4, stream);
  hipMemsetAsync(counts, 0, (size_t)(NBOOKS + 2) * 4, stream);

  // weights -> bf16, then MFMA GEMMs
  cast_w<<<(HID * FEAT + 255) / 256, 256, 0, stream>>>(user_W, book_W, wub, wbb);
  gemm_mfma<<<(NUSERS + 127) / 128, 256, 0, stream>>>(user_x, wub, user_b, cu0, cu0b, NUSERS, 1.0f);
  gemm_mfma<<<(NBOOKS + 127) / 128, 256, 0, stream>>>(book_x, wbb, book_b, out_book, (unsigned short*)nullptr, NBOOKS, 1.0f / 3.0f);

  // degrees / norms
  const int nthr = 2 * EPR;
  deg_kernel<<<(nthr + 255) / 256, 256, 0, stream>>>(rates, impl, degi);
  dis_kernel<<<(NUSERS + 255) / 256, 256, 0, stream>>>(degi, dis, NUSERS);

  // CSR over forward edges (dest = raw book id < NBOOKS)
  count_kernel<<<(nthr + 255) / 256, 256, 0, stream>>>(rates, impl, dis, counts);
  const int nb = (NBOOKS + 1023) / 1024;
  scan_blocks<<<nb, 1024, 0, stream>>>(counts, offs, bsum, NBOOKS);
  scan_totals<<<1, 64, 0, stream>>>(bsum, bpre, offs, nb, NBOOKS);
  add_prefix<<<(NBOOKS + 255) / 256, 256, 0, stream>>>(offs, bpre, NBOOKS);
  hipMemcpyAsync(cur, offs, (size_t)NBOOKS * 4, hipMemcpyDeviceToDevice, stream);
  fill_kernel<<<(nthr + 255) / 256, 256, 0, stream>>>(rates, impl, dis, cur, brow, bnorm);

  // users >= NBOOKS: no incoming messages ever; also zeroes h1b upper rows
  upper_users<<<NUSERS - NBOOKS, 128, 0, stream>>>(cu0, h1b, out_user);

  // propagation (dests < NBOOKS only), layer 2 fuses final mean
  pull1<<<NBOOKS, 128, 0, stream>>>(cu0b, offs, brow, bnorm, h1, h1b);
  pull2_final<<<NBOOKS, 128, 0, stream>>>(h1b, offs, brow, bnorm, cu0, h1, out_user);
}

// Round 3
// 439.863 us; speedup vs baseline: 1.3862x; 1.0645x over previous
//
#include <hip/hip_runtime.h>

#define NUSERS 100000
#define NBOOKS 50000
#define HID 128
#define FEAT 256
#define EPR 500000
#define NEDGE (2 * EPR)   // 1M original (forward) edges

typedef __attribute__((ext_vector_type(8))) short bf16x8;
typedef __attribute__((ext_vector_type(4))) float f32x4;

__device__ __forceinline__ unsigned short f2bf(float f) {
  union { float f; unsigned u; } v; v.f = f;
  unsigned r = v.u + 0x7FFFu + ((v.u >> 16) & 1u);   // RNE
  return (unsigned short)(r >> 16);
}
__device__ __forceinline__ float bf2f(unsigned short h) {
  union { unsigned u; float f; } v; v.u = ((unsigned)h) << 16;
  return v.f;
}

// ---------------------------------------------------------------------------
// Cast both weight matrices (128x256) to bf16.
// ---------------------------------------------------------------------------
__global__ void cast_w(const float* __restrict__ w0, const float* __restrict__ w1,
                       unsigned short* __restrict__ o0, unsigned short* __restrict__ o1)
{
  int i = blockIdx.x * 256 + threadIdx.x;
  if (i < HID * FEAT) { o0[i] = f2bf(w0[i]); o1[i] = f2bf(w1[i]); }
}

// ---------------------------------------------------------------------------
// Merged MFMA GEMM for users+books: C = (X @ W^T + b) [* scale].
// Blocks [0, UB) -> user rows (write bf16 cu0b), [UB, UB+BB) -> book rows
// (write fp32 out_book * 1/3).
// Block 256 thr = 4 waves; wave w owns rows [bm+32w, bm+32w+32) x all 128 cols
// = 2 x 8 frags of 16x16. K=256 fully unrolled, 1-step A prefetch.
// mfma_f32_16x16x32_bf16 layouts (verified R2):
//   A lane l: row=l&15, k=(l>>4)*8+j ; B: col=l&15, same k
//   D lane l: col=l&15, row=(l>>4)*4+j
// ---------------------------------------------------------------------------
__global__ __launch_bounds__(256) void gemm_all(
    const float* __restrict__ Xu, const float* __restrict__ Xb,
    const unsigned short* __restrict__ Wu, const unsigned short* __restrict__ Wb,
    const float* __restrict__ bu, const float* __restrict__ bb,
    unsigned short* __restrict__ cu0b, float* __restrict__ outb)
{
  const int UB = (NUSERS + 127) / 128;   // 782
  const bool isU = (int)blockIdx.x < UB;
  const float* __restrict__ X = isU ? Xu : Xb;
  const unsigned short* __restrict__ W = isU ? Wu : Wb;
  const float* __restrict__ bias = isU ? bu : bb;
  const int M  = isU ? NUSERS : NBOOKS;
  const int bm = (isU ? blockIdx.x : blockIdx.x - UB) * 128;

  const int tid  = threadIdx.x;
  const int lane = tid & 63;
  const int wv   = tid >> 6;
  const int l15  = lane & 15, l4 = lane >> 4;
  const int row0 = bm + wv * 32;

  int r[2]; bool rok[2];
#pragma unroll
  for (int mi = 0; mi < 2; ++mi) { r[mi] = row0 + mi * 16 + l15; rok[mi] = r[mi] < M; }

  f32x4 acc[2][8];
#pragma unroll
  for (int mi = 0; mi < 2; ++mi)
#pragma unroll
    for (int ni = 0; ni < 8; ++ni) acc[mi][ni] = (f32x4)0.f;

  float4 xa[2][2];
#pragma unroll
  for (int mi = 0; mi < 2; ++mi) {
    if (rok[mi]) {
      const float4* ap = reinterpret_cast<const float4*>(&X[(size_t)r[mi] * FEAT + l4 * 8]);
      xa[mi][0] = ap[0]; xa[mi][1] = ap[1];
    } else {
      xa[mi][0] = make_float4(0.f, 0.f, 0.f, 0.f);
      xa[mi][1] = make_float4(0.f, 0.f, 0.f, 0.f);
    }
  }

#pragma unroll
  for (int ks = 0; ks < 8; ++ks) {
    float4 xn[2][2];
    if (ks < 7) {
#pragma unroll
      for (int mi = 0; mi < 2; ++mi) {
        if (rok[mi]) {
          const float4* ap = reinterpret_cast<const float4*>(
              &X[(size_t)r[mi] * FEAT + (ks + 1) * 32 + l4 * 8]);
          xn[mi][0] = ap[0]; xn[mi][1] = ap[1];
        } else {
          xn[mi][0] = make_float4(0.f, 0.f, 0.f, 0.f);
          xn[mi][1] = make_float4(0.f, 0.f, 0.f, 0.f);
        }
      }
    }
    bf16x8 a[2];
#pragma unroll
    for (int mi = 0; mi < 2; ++mi) {
      bf16x8 av;
      av[0] = (short)f2bf(xa[mi][0].x); av[1] = (short)f2bf(xa[mi][0].y);
      av[2] = (short)f2bf(xa[mi][0].z); av[3] = (short)f2bf(xa[mi][0].w);
      av[4] = (short)f2bf(xa[mi][1].x); av[5] = (short)f2bf(xa[mi][1].y);
      av[6] = (short)f2bf(xa[mi][1].z); av[7] = (short)f2bf(xa[mi][1].w);
      a[mi] = av;
    }
#pragma unroll
    for (int ni = 0; ni < 8; ++ni) {
      int col = ni * 16 + l15;
      bf16x8 bfr = *reinterpret_cast<const bf16x8*>(&W[(size_t)col * FEAT + ks * 32 + l4 * 8]);
      acc[0][ni] = __builtin_amdgcn_mfma_f32_16x16x32_bf16(a[0], bfr, acc[0][ni], 0, 0, 0);
      acc[1][ni] = __builtin_amdgcn_mfma_f32_16x16x32_bf16(a[1], bfr, acc[1][ni], 0, 0, 0);
    }
    if (ks < 7) {
#pragma unroll
      for (int mi = 0; mi < 2; ++mi) { xa[mi][0] = xn[mi][0]; xa[mi][1] = xn[mi][1]; }
    }
  }

#pragma unroll
  for (int ni = 0; ni < 8; ++ni) {
    int col = ni * 16 + l15;
    float bj = bias[col];
#pragma unroll
    for (int mi = 0; mi < 2; ++mi) {
#pragma unroll
      for (int j = 0; j < 4; ++j) {
        int rr = row0 + mi * 16 + l4 * 4 + j;
        if (rr < M) {
          float vv = acc[mi][ni][j] + bj;
          if (isU) cu0b[(size_t)rr * HID + col] = f2bf(vv);
          else     outb[(size_t)rr * HID + col] = vv * (1.0f / 3.0f);
        }
      }
    }
  }
}

// ---------------------------------------------------------------------------
// Graph preprocessing. All forward edges (row=u, col=bk) have nonzero norm
// (each endpoint's degree >= 1 from this very edge pair); reverse edges have
// norm exactly 0 (source node NUSERS+bk never appears as a col -> deg 0).
// ---------------------------------------------------------------------------
__device__ __forceinline__ void decode_edge(const int* __restrict__ rates,
                                            const int* __restrict__ impl,
                                            int i, int& u, int& bk)
{
  if (i < EPR) { u = rates[i]; bk = rates[EPR + i]; }
  else { int j = i - EPR; u = impl[j]; bk = impl[EPR + j]; }
}

__global__ void deg_count(const int* __restrict__ rates, const int* __restrict__ impl,
                          int* __restrict__ deg, int* __restrict__ counts)
{
  int i = blockIdx.x * blockDim.x + threadIdx.x;
  if (i >= NEDGE) return;
  int u, bk;
  decode_edge(rates, impl, i, u, bk);
  atomicAdd(&deg[bk], 1);     // forward edge's col
  atomicAdd(&deg[u], 1);      // reverse edge's col
  atomicAdd(&counts[bk], 1);  // CSR count (all forward edges kept)
}

__global__ void dis_kernel(const int* __restrict__ deg, float* __restrict__ dis, int n)
{
  int i = blockIdx.x * blockDim.x + threadIdx.x;
  if (i < n) {
    int d = deg[i];
    dis[i] = (d > 0) ? rsqrtf((float)d) : 0.f;
  }
}

__global__ void fill_kernel(const int* __restrict__ rates, const int* __restrict__ impl,
                            const float* __restrict__ dis, int* __restrict__ cur,
                            int* __restrict__ brow, float* __restrict__ bnorm)
{
  int i = blockIdx.x * blockDim.x + threadIdx.x;
  if (i >= NEDGE) return;
  int u, bk;
  decode_edge(rates, impl, i, u, bk);
  float nf = dis[u] * dis[bk];
  int pos = atomicAdd(&cur[bk], 1);
  brow[pos] = u; bnorm[pos] = nf;
}

// ---------------------------------------------------------------------------
// Exclusive scan of counts[0..N) -> offs[0..N]
// ---------------------------------------------------------------------------
__global__ __launch_bounds__(1024) void scan_blocks(const int* __restrict__ counts,
                                                    int* __restrict__ offs,
                                                    int* __restrict__ bsum, int N)
{
  __shared__ int buf[1024];
  int t = threadIdx.x;
  int i = blockIdx.x * 1024 + t;
  int v = (i < N) ? counts[i] : 0;
  buf[t] = v;
  __syncthreads();
  for (int off = 1; off < 1024; off <<= 1) {
    int x = (t >= off) ? buf[t - off] : 0;
    __syncthreads();
    buf[t] += x;
    __syncthreads();
  }
  int incl = buf[t];
  if (i < N) offs[i] = incl - v;
  if (t == 1023) bsum[blockIdx.x] = incl;
}

__global__ void scan_totals(const int* __restrict__ bsum, int* __restrict__ bpre,
                            int* __restrict__ offs, int nb, int N)
{
  if (threadIdx.x == 0 && blockIdx.x == 0) {
    int run = 0;
    for (int b = 0; b < nb; ++b) { bpre[b] = run; run += bsum[b]; }
    offs[N] = run;
  }
}

__global__ void add_prefix(int* __restrict__ offs, const int* __restrict__ bpre, int N)
{
  int i = blockIdx.x * blockDim.x + threadIdx.x;
  if (i < N) offs[i] += bpre[i >> 10];
}

// ---------------------------------------------------------------------------
// Pull aggregation: one WAVE per dest (64 lanes x ushort2 = 128 feats).
// Block 256 = 4 dests. Sources bf16.
// ---------------------------------------------------------------------------
__global__ __launch_bounds__(256) void pull1(const unsigned short* __restrict__ srcb,
    const int* __restrict__ offs, const int* __restrict__ brow,
    const float* __restrict__ bnorm, unsigned short* __restrict__ dstb)
{
  int c = (blockIdx.x << 2) + (threadIdx.x >> 6);
  if (c >= NBOOKS) return;
  int lane = threadIdx.x & 63;
  int base = lane * 2;
  int s = offs[c], e = offs[c + 1];
  float a0 = 0.f, a1 = 0.f;
  int i = s;
  for (; i + 4 <= e; i += 4) {
#pragma unroll
    for (int q = 0; q < 4; ++q) {
      int   rr = brow[i + q];
      float wq = bnorm[i + q];
      ushort2 v = *reinterpret_cast<const ushort2*>(&srcb[(size_t)rr * HID + base]);
      a0 += wq * bf2f(v.x);
      a1 += wq * bf2f(v.y);
    }
  }
  for (; i < e; ++i) {
    int rr = brow[i]; float wq = bnorm[i];
    ushort2 v = *reinterpret_cast<const ushort2*>(&srcb[(size_t)rr * HID + base]);
    a0 += wq * bf2f(v.x);
    a1 += wq * bf2f(v.y);
  }
  ushort2 o; o.x = f2bf(a0); o.y = f2bf(a1);
  *reinterpret_cast<ushort2*>(&dstb[(size_t)c * HID + base]) = o;
}

// Layer 2 + final mean for dests < NBOOKS. Gathers h1b (only rows < NBOOKS are
// nonzero -> skip others; branch is wave-uniform). Epilogue uses bf16 cu0b/h1b.
__global__ __launch_bounds__(256) void pull2_final(const unsigned short* __restrict__ h1b,
    const int* __restrict__ offs, const int* __restrict__ brow,
    const float* __restrict__ bnorm, const unsigned short* __restrict__ cu0b,
    float* __restrict__ outu)
{
  int c = (blockIdx.x << 2) + (threadIdx.x >> 6);
  if (c >= NBOOKS) return;
  int lane = threadIdx.x & 63;
  int base = lane * 2;
  int s = offs[c], e = offs[c + 1];
  float a0 = 0.f, a1 = 0.f;
  for (int i = s; i < e; ++i) {
    int rr = brow[i];
    if (rr < NBOOKS) {
      float wq = bnorm[i];
      ushort2 v = *reinterpret_cast<const ushort2*>(&h1b[(size_t)rr * HID + base]);
      a0 += wq * bf2f(v.x);
      a1 += wq * bf2f(v.y);
    }
  }
  size_t idx = (size_t)c * HID + base;
  ushort2 c0 = *reinterpret_cast<const ushort2*>(&cu0b[idx]);
  ushort2 h1 = *reinterpret_cast<const ushort2*>(&h1b[idx]);
  float2 o;
  o.x = (bf2f(c0.x) + bf2f(h1.x) + a0) * (1.0f / 3.0f);
  o.y = (bf2f(c0.y) + bf2f(h1.y) + a1) * (1.0f / 3.0f);
  *reinterpret_cast<float2*>(&outu[idx]) = o;
}

// Users [NBOOKS, NUSERS): never receive messages -> out = cu0/3.
__global__ __launch_bounds__(256) void upper_users(const unsigned short* __restrict__ cu0b,
                                                   float* __restrict__ outu)
{
  size_t i2 = (size_t)blockIdx.x * 256 + threadIdx.x;             // ushort2 index
  size_t off2 = (size_t)NBOOKS * HID / 2;
  size_t idx = (off2 + i2) * 2;
  ushort2 v = *reinterpret_cast<const ushort2*>(&cu0b[idx]);
  float2 o;
  o.x = bf2f(v.x) * (1.0f / 3.0f);
  o.y = bf2f(v.y) * (1.0f / 3.0f);
  *reinterpret_cast<float2*>(&outu[idx]) = o;
}

// ---------------------------------------------------------------------------
extern "C" void kernel_launch(void* const* d_in, const int* in_sizes, int n_in,
                              void* d_out, int out_size, void* d_ws, size_t ws_size,
                              hipStream_t stream)
{
  const float* user_x = (const float*)d_in[0];
  const float* book_x = (const float*)d_in[1];
  const float* user_W = (const float*)d_in[2];
  const float* user_b = (const float*)d_in[3];
  const float* book_W = (const float*)d_in[4];
  const float* book_b = (const float*)d_in[5];
  const int*   rates  = (const int*)d_in[6];
  const int*   impl   = (const int*)d_in[7];

  float* out      = (float*)d_out;
  float* out_user = out;
  float* out_book = out + (size_t)NUSERS * HID;

  char* p = (char*)d_ws;
  auto carve = [&](size_t bytes) -> void* {
    void* r = (void*)p;
    p += (bytes + 255) & ~(size_t)255;
    return r;
  };
  unsigned short* cu0b  = (unsigned short*)carve((size_t)NUSERS * HID * 2);
  unsigned short* h1b   = (unsigned short*)carve((size_t)NBOOKS * HID * 2);
  unsigned short* wub   = (unsigned short*)carve((size_t)HID * FEAT * 2);
  unsigned short* wbb   = (unsigned short*)carve((size_t)HID * FEAT * 2);
  int*   degi   = (int*)carve((size_t)NUSERS * 4);
  float* dis    = (float*)carve((size_t)NUSERS * 4);
  int*   counts = (int*)carve((size_t)(NBOOKS + 2) * 4);
  int*   offs   = (int*)carve((size_t)(NBOOKS + 2) * 4);
  int*   bsum   = (int*)carve(256 * 4);
  int*   bpre   = (int*)carve(256 * 4);
  int*   cur    = (int*)carve((size_t)NBOOKS * 4);
  int*   brow   = (int*)carve((size_t)NEDGE * 4);
  float* bnorm  = (float*)carve((size_t)NEDGE * 4);

  hipMemsetAsync(degi, 0, (size_t)NUSERS * 4, stream);
  hipMemsetAsync(counts, 0, (size_t)(NBOOKS + 2) * 4, stream);

  // weights -> bf16, merged MFMA GEMM
  cast_w<<<(HID * FEAT + 255) / 256, 256, 0, stream>>>(user_W, book_W, wub, wbb);
  const int UB = (NUSERS + 127) / 128, BB = (NBOOKS + 127) / 128;
  gemm_all<<<UB + BB, 256, 0, stream>>>(user_x, book_x, wub, wbb, user_b, book_b,
                                        cu0b, out_book);

  // degrees / norms / CSR
  deg_count<<<(NEDGE + 255) / 256, 256, 0, stream>>>(rates, impl, degi, counts);
  dis_kernel<<<(NUSERS + 255) / 256, 256, 0, stream>>>(degi, dis, NUSERS);
  const int nb = (NBOOKS + 1023) / 1024;
  scan_blocks<<<nb, 1024, 0, stream>>>(counts, offs, bsum, NBOOKS);
  scan_totals<<<1, 64, 0, stream>>>(bsum, bpre, offs, nb, NBOOKS);
  add_prefix<<<(NBOOKS + 255) / 256, 256, 0, stream>>>(offs, bpre, NBOOKS);
  hipMemcpyAsync(cur, offs, (size_t)NBOOKS * 4, hipMemcpyDeviceToDevice, stream);
  fill_kernel<<<(NEDGE + 255) / 256, 256, 0, stream>>>(rates, impl, dis, cur, brow, bnorm);

  // users >= NBOOKS get cu0/3 directly
  upper_users<<<(NUSERS - NBOOKS) * HID / 512, 256, 0, stream>>>(cu0b, out_user);

  // propagation (dests < NBOOKS), layer 2 fuses final mean
  pull1<<<(NBOOKS + 3) / 4, 256, 0, stream>>>(cu0b, offs, brow, bnorm, h1b);
  pull2_final<<<(NBOOKS + 3) / 4, 256, 0, stream>>>(h1b, offs, brow, bnorm, cu0b, out_user);
}

// Round 4
// 304.932 us; speedup vs baseline: 1.9996x; 1.4425x over previous
//
#include <hip/hip_runtime.h>

#define NUSERS 100000
#define NBOOKS 50000
#define HID 128
#define FEAT 256
#define EPR 500000
#define NEDGE (2 * EPR)   // 1M forward edges (reverse edges have norm == 0)

typedef __attribute__((ext_vector_type(8))) short bf16x8;
typedef __attribute__((ext_vector_type(4))) float f32x4;

__device__ __forceinline__ unsigned short f2bf(float f) {
  union { float f; unsigned u; } v; v.f = f;
  unsigned r = v.u + 0x7FFFu + ((v.u >> 16) & 1u);   // RNE
  return (unsigned short)(r >> 16);
}
__device__ __forceinline__ float bf2f(unsigned short h) {
  union { unsigned u; float f; } v; v.u = ((unsigned)h) << 16;
  return v.f;
}

// ---------------------------------------------------------------------------
__global__ void cast_w(const float* __restrict__ w0, const float* __restrict__ w1,
                       unsigned short* __restrict__ o0, unsigned short* __restrict__ o1)
{
  int i = blockIdx.x * 256 + threadIdx.x;
  if (i < HID * FEAT) { o0[i] = f2bf(w0[i]); o1[i] = f2bf(w1[i]); }
}

// ---------------------------------------------------------------------------
// Merged MFMA GEMM (users -> bf16 cu0b, books -> fp32 out_book * 1/3).
// Unchanged from R3 (validated).
// ---------------------------------------------------------------------------
__global__ __launch_bounds__(256) void gemm_all(
    const float* __restrict__ Xu, const float* __restrict__ Xb,
    const unsigned short* __restrict__ Wu, const unsigned short* __restrict__ Wb,
    const float* __restrict__ bu, const float* __restrict__ bb,
    unsigned short* __restrict__ cu0b, float* __restrict__ outb)
{
  const int UB = (NUSERS + 127) / 128;
  const bool isU = (int)blockIdx.x < UB;
  const float* __restrict__ X = isU ? Xu : Xb;
  const unsigned short* __restrict__ W = isU ? Wu : Wb;
  const float* __restrict__ bias = isU ? bu : bb;
  const int M  = isU ? NUSERS : NBOOKS;
  const int bm = (isU ? blockIdx.x : blockIdx.x - UB) * 128;

  const int tid  = threadIdx.x;
  const int lane = tid & 63;
  const int wv   = tid >> 6;
  const int l15  = lane & 15, l4 = lane >> 4;
  const int row0 = bm + wv * 32;

  int r[2]; bool rok[2];
#pragma unroll
  for (int mi = 0; mi < 2; ++mi) { r[mi] = row0 + mi * 16 + l15; rok[mi] = r[mi] < M; }

  f32x4 acc[2][8];
#pragma unroll
  for (int mi = 0; mi < 2; ++mi)
#pragma unroll
    for (int ni = 0; ni < 8; ++ni) acc[mi][ni] = (f32x4)0.f;

  float4 xa[2][2];
#pragma unroll
  for (int mi = 0; mi < 2; ++mi) {
    if (rok[mi]) {
      const float4* ap = reinterpret_cast<const float4*>(&X[(size_t)r[mi] * FEAT + l4 * 8]);
      xa[mi][0] = ap[0]; xa[mi][1] = ap[1];
    } else {
      xa[mi][0] = make_float4(0.f, 0.f, 0.f, 0.f);
      xa[mi][1] = make_float4(0.f, 0.f, 0.f, 0.f);
    }
  }

#pragma unroll
  for (int ks = 0; ks < 8; ++ks) {
    float4 xn[2][2];
    if (ks < 7) {
#pragma unroll
      for (int mi = 0; mi < 2; ++mi) {
        if (rok[mi]) {
          const float4* ap = reinterpret_cast<const float4*>(
              &X[(size_t)r[mi] * FEAT + (ks + 1) * 32 + l4 * 8]);
          xn[mi][0] = ap[0]; xn[mi][1] = ap[1];
        } else {
          xn[mi][0] = make_float4(0.f, 0.f, 0.f, 0.f);
          xn[mi][1] = make_float4(0.f, 0.f, 0.f, 0.f);
        }
      }
    }
    bf16x8 a[2];
#pragma unroll
    for (int mi = 0; mi < 2; ++mi) {
      bf16x8 av;
      av[0] = (short)f2bf(xa[mi][0].x); av[1] = (short)f2bf(xa[mi][0].y);
      av[2] = (short)f2bf(xa[mi][0].z); av[3] = (short)f2bf(xa[mi][0].w);
      av[4] = (short)f2bf(xa[mi][1].x); av[5] = (short)f2bf(xa[mi][1].y);
      av[6] = (short)f2bf(xa[mi][1].z); av[7] = (short)f2bf(xa[mi][1].w);
      a[mi] = av;
    }
#pragma unroll
    for (int ni = 0; ni < 8; ++ni) {
      int col = ni * 16 + l15;
      bf16x8 bfr = *reinterpret_cast<const bf16x8*>(&W[(size_t)col * FEAT + ks * 32 + l4 * 8]);
      acc[0][ni] = __builtin_amdgcn_mfma_f32_16x16x32_bf16(a[0], bfr, acc[0][ni], 0, 0, 0);
      acc[1][ni] = __builtin_amdgcn_mfma_f32_16x16x32_bf16(a[1], bfr, acc[1][ni], 0, 0, 0);
    }
    if (ks < 7) {
#pragma unroll
      for (int mi = 0; mi < 2; ++mi) { xa[mi][0] = xn[mi][0]; xa[mi][1] = xn[mi][1]; }
    }
  }

#pragma unroll
  for (int ni = 0; ni < 8; ++ni) {
    int col = ni * 16 + l15;
    float bj = bias[col];
#pragma unroll
    for (int mi = 0; mi < 2; ++mi) {
#pragma unroll
      for (int j = 0; j < 4; ++j) {
        int rr = row0 + mi * 16 + l4 * 4 + j;
        if (rr < M) {
          float vv = acc[mi][ni][j] + bj;
          if (isU) cu0b[(size_t)rr * HID + col] = f2bf(vv);
          else     outb[(size_t)rr * HID + col] = vv * (1.0f / 3.0f);
        }
      }
    }
  }
}

// ---------------------------------------------------------------------------
// Graph preprocessing, minimal-atomic form.
// Node degree decomposition: deg[n] = degu[n] + (n < NBOOKS ? cntb[n] : 0)
//   degu[u]  = # edges with user endpoint u   (reverse-edge cols)
//   cntb[bk] = # edges with book endpoint bk  (forward-edge cols) = CSR counts
// relpos[i] = this edge's slot within bucket bk (atomic return value).
// ---------------------------------------------------------------------------
__device__ __forceinline__ void decode_edge(const int* __restrict__ rates,
                                            const int* __restrict__ impl,
                                            int i, int& u, int& bk)
{
  if (i < EPR) { u = rates[i]; bk = rates[EPR + i]; }
  else { int j = i - EPR; u = impl[j]; bk = impl[EPR + j]; }
}

__global__ void hist_kernel(const int* __restrict__ rates, const int* __restrict__ impl,
                            int* __restrict__ degu, int* __restrict__ cntb,
                            unsigned int* __restrict__ relpos)
{
  int i = blockIdx.x * blockDim.x + threadIdx.x;
  if (i >= NEDGE) return;
  int u, bk;
  decode_edge(rates, impl, i, u, bk);
  relpos[i] = (unsigned int)atomicAdd(&cntb[bk], 1);
  atomicAdd(&degu[u], 1);
}

__global__ void dis_kernel(const int* __restrict__ degu, const int* __restrict__ cntb,
                           float* __restrict__ dis)
{
  int i = blockIdx.x * blockDim.x + threadIdx.x;
  if (i < NUSERS) {
    int d = degu[i] + (i < NBOOKS ? cntb[i] : 0);
    dis[i] = (d > 0) ? rsqrtf((float)d) : 0.f;
  }
}

__global__ void fill_scatter(const int* __restrict__ rates, const int* __restrict__ impl,
                             const int* __restrict__ offs,
                             const unsigned int* __restrict__ relpos,
                             int* __restrict__ brow)
{
  int i = blockIdx.x * blockDim.x + threadIdx.x;
  if (i >= NEDGE) return;
  int u, bk;
  decode_edge(rates, impl, i, u, bk);
  brow[offs[bk] + (int)relpos[i]] = u;
}

// ---------------------------------------------------------------------------
// Exclusive scan of cntb[0..N) -> offs[0..N]
// ---------------------------------------------------------------------------
__global__ __launch_bounds__(1024) void scan_blocks(const int* __restrict__ counts,
                                                    int* __restrict__ offs,
                                                    int* __restrict__ bsum, int N)
{
  __shared__ int buf[1024];
  int t = threadIdx.x;
  int i = blockIdx.x * 1024 + t;
  int v = (i < N) ? counts[i] : 0;
  buf[t] = v;
  __syncthreads();
  for (int off = 1; off < 1024; off <<= 1) {
    int x = (t >= off) ? buf[t - off] : 0;
    __syncthreads();
    buf[t] += x;
    __syncthreads();
  }
  int incl = buf[t];
  if (i < N) offs[i] = incl - v;
  if (t == 1023) bsum[blockIdx.x] = incl;
}

__global__ void scan_totals(const int* __restrict__ bsum, int* __restrict__ bpre,
                            int* __restrict__ offs, int nb, int N)
{
  if (threadIdx.x == 0 && blockIdx.x == 0) {
    int run = 0;
    for (int b = 0; b < nb; ++b) { bpre[b] = run; run += bsum[b]; }
    offs[N] = run;
  }
}

__global__ void add_prefix(int* __restrict__ offs, const int* __restrict__ bpre, int N)
{
  int i = blockIdx.x * blockDim.x + threadIdx.x;
  if (i < N) offs[i] += bpre[i >> 10];
}

// ---------------------------------------------------------------------------
// Pull layer 1: wave per dest, 4 lane-groups of 16, each group loads full
// 256B rows (16 x dwordx4); 2x unroll = 8 rows in flight. Cross-group reduce
// via shfl_xor(16|32). h1[c] = dis[c] * sum_u dis[u] * cu0[u].
// ---------------------------------------------------------------------------
__global__ __launch_bounds__(256) void pull1(const unsigned short* __restrict__ srcb,
    const int* __restrict__ offs, const int* __restrict__ brow,
    const float* __restrict__ dis, unsigned short* __restrict__ dstb)
{
  int c = (blockIdx.x << 2) + (threadIdx.x >> 6);
  if (c >= NBOOKS) return;
  const int lane = threadIdx.x & 63;
  const int g = lane >> 4, l = lane & 15;
  const int s = offs[c], e = offs[c + 1];

  float acc[8];
#pragma unroll
  for (int j = 0; j < 8; ++j) acc[j] = 0.f;

  int i = s + g;
  for (; i + 4 < e; i += 8) {
    int rr0 = brow[i], rr1 = brow[i + 4];
    float w0 = dis[rr0], w1 = dis[rr1];
    bf16x8 v0 = *reinterpret_cast<const bf16x8*>(&srcb[(size_t)rr0 * HID + l * 8]);
    bf16x8 v1 = *reinterpret_cast<const bf16x8*>(&srcb[(size_t)rr1 * HID + l * 8]);
#pragma unroll
    for (int j = 0; j < 8; ++j) acc[j] += w0 * bf2f((unsigned short)v0[j]);
#pragma unroll
    for (int j = 0; j < 8; ++j) acc[j] += w1 * bf2f((unsigned short)v1[j]);
  }
  if (i < e) {
    int rr = brow[i];
    float w = dis[rr];
    bf16x8 v = *reinterpret_cast<const bf16x8*>(&srcb[(size_t)rr * HID + l * 8]);
#pragma unroll
    for (int j = 0; j < 8; ++j) acc[j] += w * bf2f((unsigned short)v[j]);
  }

#pragma unroll
  for (int j = 0; j < 8; ++j) {
    acc[j] += __shfl_xor(acc[j], 16, 64);
    acc[j] += __shfl_xor(acc[j], 32, 64);
  }
  if (g == 0) {
    float db = dis[c];
    bf16x8 o;
#pragma unroll
    for (int j = 0; j < 8; ++j) o[j] = (short)f2bf(db * acc[j]);
    *reinterpret_cast<bf16x8*>(&dstb[(size_t)c * HID + l * 8]) = o;
  }
}

// Layer 2 + final mean. Sources: h1 rows (< NBOOKS only; others are zero ->
// branchless clamped gather with weight 0). out = (cu0 + h1 + dis[c]*acc)/3.
__global__ __launch_bounds__(256) void pull2_final(const unsigned short* __restrict__ h1b,
    const int* __restrict__ offs, const int* __restrict__ brow,
    const float* __restrict__ dis, const unsigned short* __restrict__ cu0b,
    float* __restrict__ outu)
{
  int c = (blockIdx.x << 2) + (threadIdx.x >> 6);
  if (c >= NBOOKS) return;
  const int lane = threadIdx.x & 63;
  const int g = lane >> 4, l = lane & 15;
  const int s = offs[c], e = offs[c + 1];

  float acc[8];
#pragma unroll
  for (int j = 0; j < 8; ++j) acc[j] = 0.f;

  int i = s + g;
  for (; i + 4 < e; i += 8) {
    int rr0 = brow[i], rr1 = brow[i + 4];
    int rc0 = rr0 < NBOOKS ? rr0 : 0;
    int rc1 = rr1 < NBOOKS ? rr1 : 0;
    float w0 = rr0 < NBOOKS ? dis[rr0] : 0.f;
    float w1 = rr1 < NBOOKS ? dis[rr1] : 0.f;
    bf16x8 v0 = *reinterpret_cast<const bf16x8*>(&h1b[(size_t)rc0 * HID + l * 8]);
    bf16x8 v1 = *reinterpret_cast<const bf16x8*>(&h1b[(size_t)rc1 * HID + l * 8]);
#pragma unroll
    for (int j = 0; j < 8; ++j) acc[j] += w0 * bf2f((unsigned short)v0[j]);
#pragma unroll
    for (int j = 0; j < 8; ++j) acc[j] += w1 * bf2f((unsigned short)v1[j]);
  }
  if (i < e) {
    int rr = brow[i];
    int rc = rr < NBOOKS ? rr : 0;
    float w = rr < NBOOKS ? dis[rr] : 0.f;
    bf16x8 v = *reinterpret_cast<const bf16x8*>(&h1b[(size_t)rc * HID + l * 8]);
#pragma unroll
    for (int j = 0; j < 8; ++j) acc[j] += w * bf2f((unsigned short)v[j]);
  }

#pragma unroll
  for (int j = 0; j < 8; ++j) {
    acc[j] += __shfl_xor(acc[j], 16, 64);
    acc[j] += __shfl_xor(acc[j], 32, 64);
  }
  if (g == 0) {
    float db = dis[c];
    size_t idx = (size_t)c * HID + l * 8;
    bf16x8 c0 = *reinterpret_cast<const bf16x8*>(&cu0b[idx]);
    bf16x8 h1 = *reinterpret_cast<const bf16x8*>(&h1b[idx]);
    float4 o0, o1;
    float r[8];
#pragma unroll
    for (int j = 0; j < 8; ++j)
      r[j] = (bf2f((unsigned short)c0[j]) + bf2f((unsigned short)h1[j]) + db * acc[j]) * (1.0f / 3.0f);
    o0 = make_float4(r[0], r[1], r[2], r[3]);
    o1 = make_float4(r[4], r[5], r[6], r[7]);
    *reinterpret_cast<float4*>(&outu[idx])     = o0;
    *reinterpret_cast<float4*>(&outu[idx + 4]) = o1;
  }
}

// Users [NBOOKS, NUSERS): out = cu0/3.
__global__ __launch_bounds__(256) void upper_users(const unsigned short* __restrict__ cu0b,
                                                   float* __restrict__ outu)
{
  size_t i2 = (size_t)blockIdx.x * 256 + threadIdx.x;
  size_t off2 = (size_t)NBOOKS * HID / 2;
  size_t idx = (off2 + i2) * 2;
  ushort2 v = *reinterpret_cast<const ushort2*>(&cu0b[idx]);
  float2 o;
  o.x = bf2f(v.x) * (1.0f / 3.0f);
  o.y = bf2f(v.y) * (1.0f / 3.0f);
  *reinterpret_cast<float2*>(&outu[idx]) = o;
}

// ---------------------------------------------------------------------------
extern "C" void kernel_launch(void* const* d_in, const int* in_sizes, int n_in,
                              void* d_out, int out_size, void* d_ws, size_t ws_size,
                              hipStream_t stream)
{
  const float* user_x = (const float*)d_in[0];
  const float* book_x = (const float*)d_in[1];
  const float* user_W = (const float*)d_in[2];
  const float* user_b = (const float*)d_in[3];
  const float* book_W = (const float*)d_in[4];
  const float* book_b = (const float*)d_in[5];
  const int*   rates  = (const int*)d_in[6];
  const int*   impl   = (const int*)d_in[7];

  float* out      = (float*)d_out;
  float* out_user = out;
  float* out_book = out + (size_t)NUSERS * HID;

  char* p = (char*)d_ws;
  auto carve = [&](size_t bytes) -> void* {
    void* r = (void*)p;
    p += (bytes + 255) & ~(size_t)255;
    return r;
  };
  unsigned short* cu0b   = (unsigned short*)carve((size_t)NUSERS * HID * 2);
  unsigned short* h1b    = (unsigned short*)carve((size_t)NBOOKS * HID * 2);
  unsigned short* wub    = (unsigned short*)carve((size_t)HID * FEAT * 2);
  unsigned short* wbb    = (unsigned short*)carve((size_t)HID * FEAT * 2);
  int*          degu   = (int*)carve((size_t)NUSERS * 4);
  int*          cntb   = (int*)carve((size_t)NBOOKS * 4);
  float*        dis    = (float*)carve((size_t)NUSERS * 4);
  int*          offs   = (int*)carve((size_t)(NBOOKS + 2) * 4);
  int*          bsum   = (int*)carve(256 * 4);
  int*          bpre   = (int*)carve(256 * 4);
  unsigned int* relpos = (unsigned int*)carve((size_t)NEDGE * 4);
  int*          brow   = (int*)carve((size_t)NEDGE * 4);

  hipMemsetAsync(degu, 0, (size_t)NUSERS * 4, stream);
  hipMemsetAsync(cntb, 0, (size_t)NBOOKS * 4, stream);

  // weights -> bf16, merged MFMA GEMM
  cast_w<<<(HID * FEAT + 255) / 256, 256, 0, stream>>>(user_W, book_W, wub, wbb);
  const int UB = (NUSERS + 127) / 128, BB = (NBOOKS + 127) / 128;
  gemm_all<<<UB + BB, 256, 0, stream>>>(user_x, book_x, wub, wbb, user_b, book_b,
                                        cu0b, out_book);

  // histogram (2 atomics/edge) + relpos
  hist_kernel<<<(NEDGE + 255) / 256, 256, 0, stream>>>(rates, impl, degu, cntb, relpos);
  dis_kernel<<<(NUSERS + 255) / 256, 256, 0, stream>>>(degu, cntb, dis);

  // scan cntb -> offs, then atomic-free scatter fill
  const int nb = (NBOOKS + 1023) / 1024;
  scan_blocks<<<nb, 1024, 0, stream>>>(cntb, offs, bsum, NBOOKS);
  scan_totals<<<1, 64, 0, stream>>>(bsum, bpre, offs, nb, NBOOKS);
  add_prefix<<<(NBOOKS + 255) / 256, 256, 0, stream>>>(offs, bpre, NBOOKS);
  fill_scatter<<<(NEDGE + 255) / 256, 256, 0, stream>>>(rates, impl, offs, relpos, brow);

  // users >= NBOOKS get cu0/3 directly
  upper_users<<<(NUSERS - NBOOKS) * HID / 512, 256, 0, stream>>>(cu0b, out_user);

  // propagation (dests < NBOOKS), layer 2 fuses final mean
  pull1<<<(NBOOKS + 3) / 4, 256, 0, stream>>>(cu0b, offs, brow, dis, h1b);
  pull2_final<<<(NBOOKS + 3) / 4, 256, 0, stream>>>(h1b, offs, brow, dis, cu0b, out_user);
}

// Round 5
// 258.863 us; speedup vs baseline: 2.3555x; 1.1780x over previous
//
#include <hip/hip_runtime.h>

#define NUSERS 100000
#define NBOOKS 50000
#define HID 128
#define FEAT 256
#define EPR 500000
#define NEDGE (2 * EPR)   // 1M forward edges (reverse edges have norm == 0)

#define UBLK ((NUSERS + 127) / 128)        // 782
#define BBLK ((NBOOKS + 127) / 128)        // 391
#define GEMM_BLOCKS (UBLK + BBLK)          // 1173
#define HIST_BLOCKS ((NEDGE + 1023) / 1024) // 977

typedef __attribute__((ext_vector_type(8))) short bf16x8;
typedef __attribute__((ext_vector_type(4))) float f32x4;

__device__ __forceinline__ unsigned short f2bf(float f) {
  union { float f; unsigned u; } v; v.f = f;
  unsigned r = v.u + 0x7FFFu + ((v.u >> 16) & 1u);   // RNE
  return (unsigned short)(r >> 16);
}
__device__ __forceinline__ float bf2f(unsigned short h) {
  union { unsigned u; float f; } v; v.u = ((unsigned)h) << 16;
  return v.f;
}

// ---------------------------------------------------------------------------
__global__ void cast_w(const float* __restrict__ w0, const float* __restrict__ w1,
                       unsigned short* __restrict__ o0, unsigned short* __restrict__ o1)
{
  int i = blockIdx.x * 256 + threadIdx.x;
  if (i < HID * FEAT) { o0[i] = f2bf(w0[i]); o1[i] = f2bf(w1[i]); }
}

// ---------------------------------------------------------------------------
__device__ __forceinline__ void decode_edge(const int* __restrict__ rates,
                                            const int* __restrict__ impl,
                                            int i, int& u, int& bk)
{
  if (i < EPR) { u = rates[i]; bk = rates[EPR + i]; }
  else { int j = i - EPR; u = impl[j]; bk = impl[EPR + j]; }
}

// ---------------------------------------------------------------------------
// Fused: blocks [0, GEMM_BLOCKS) do the MFMA GEMM with async LDS staging;
// blocks [GEMM_BLOCKS, +HIST_BLOCKS) do the edge histogram (2 atomics/edge).
// The atomics' memory-side latency hides under the GEMM's streaming phase.
//
// GEMM: C = X @ W^T + b. M-tile 128 rows, K-step 32 (8 steps), 4 waves,
// wave wv owns rows [wv*32, wv*32+32) x all 128 cols (2x8 16x16x32 frags).
// A staged fp32 in LDS via global_load_lds (width 16, linear dest) with the
// 16B-slot XOR swizzle applied to the GLOBAL source (slot s of row r lives at
// physical slot s^(r&7)) so ds_read_b128 A-frag reads are 2-way (free).
// W read direct from global bf16 (64 KB, L1/L2-hot).
// User rows: write bf16 cu0b (+ fp32 out_user/3 for rows >= NBOOKS).
// Book rows: write fp32 out_book/3.
// ---------------------------------------------------------------------------
__global__ __launch_bounds__(256) void gemm_hist(
    const float* __restrict__ Xu, const float* __restrict__ Xb,
    const unsigned short* __restrict__ Wu, const unsigned short* __restrict__ Wb,
    const float* __restrict__ bu, const float* __restrict__ bb,
    unsigned short* __restrict__ cu0b, float* __restrict__ outb,
    float* __restrict__ outu,
    const int* __restrict__ rates, const int* __restrict__ impl,
    int* __restrict__ degu, int* __restrict__ cntb,
    unsigned int* __restrict__ relpos)
{
  __shared__ float Abuf[2][128 * 32];
  const int bid = blockIdx.x;
  const int tid = threadIdx.x;

  if (bid >= GEMM_BLOCKS) {
    // ---------------- histogram part ----------------
    const int hb = bid - GEMM_BLOCKS;
#pragma unroll
    for (int q = 0; q < 4; ++q) {
      int i = hb * 1024 + q * 256 + tid;
      if (i < NEDGE) {
        int u, bk;
        decode_edge(rates, impl, i, u, bk);
        relpos[i] = (unsigned int)atomicAdd(&cntb[bk], 1);
        atomicAdd(&degu[u], 1);
      }
    }
    return;
  }

  // ---------------- GEMM part ----------------
  const bool isU = bid < UBLK;
  const float* __restrict__ X = isU ? Xu : Xb;
  const unsigned short* __restrict__ W = isU ? Wu : Wb;
  const float* __restrict__ bias = isU ? bu : bb;
  const int M  = isU ? NUSERS : NBOOKS;
  const int bm = (isU ? bid : bid - UBLK) * 128;

  const int lane = tid & 63;
  const int wv   = tid >> 6;
  const int l15  = lane & 15, l4 = lane >> 4;
  const int row0 = wv * 32;

  // stage K-step ks into buffer bf: 1024 16B-units, 4 rounds of 256
  auto stage = [&](int bf, int ks) {
    const int k0 = ks * 32;
#pragma unroll
    for (int q = 0; q < 4; ++q) {
      int o = q * 256 + tid;              // linear 16B unit in LDS
      int r = o >> 3;                     // row 0..127
      int s = (o & 7) ^ (r & 7);          // logical slot (inverse swizzle)
      int gr = bm + r; if (gr > M - 1) gr = M - 1;   // clamp (rows unused)
      const float* src = &X[(size_t)gr * FEAT + k0 + s * 4];
      float* dst = &Abuf[bf][(size_t)(q * 256 + wv * 64) * 4]; // wave-uniform
      __builtin_amdgcn_global_load_lds(src, dst, 16, 0, 0);
    }
  };

  f32x4 acc[2][8];
#pragma unroll
  for (int mi = 0; mi < 2; ++mi)
#pragma unroll
    for (int ni = 0; ni < 8; ++ni) acc[mi][ni] = (f32x4)0.f;

  stage(0, 0);

#pragma unroll
  for (int ks = 0; ks < 8; ++ks) {
    if (ks < 7) stage((ks + 1) & 1, ks + 1);
    __syncthreads();                       // buf[ks&1] staged & visible
    const float* Ab = Abuf[ks & 1];

    bf16x8 bfr[8];
#pragma unroll
    for (int ni = 0; ni < 8; ++ni) {
      int col = ni * 16 + l15;
      bfr[ni] = *reinterpret_cast<const bf16x8*>(&W[(size_t)col * FEAT + ks * 32 + l4 * 8]);
    }

    bf16x8 a[2];
#pragma unroll
    for (int mi = 0; mi < 2; ++mi) {
      int rt = row0 + mi * 16 + l15;
      int m7 = rt & 7;
      int s0 = l4 * 2;
      float4 x0 = *reinterpret_cast<const float4*>(&Ab[rt * 32 + ((s0)     ^ m7) * 4]);
      float4 x1 = *reinterpret_cast<const float4*>(&Ab[rt * 32 + ((s0 + 1) ^ m7) * 4]);
      bf16x8 av;
      av[0] = (short)f2bf(x0.x); av[1] = (short)f2bf(x0.y);
      av[2] = (short)f2bf(x0.z); av[3] = (short)f2bf(x0.w);
      av[4] = (short)f2bf(x1.x); av[5] = (short)f2bf(x1.y);
      av[6] = (short)f2bf(x1.z); av[7] = (short)f2bf(x1.w);
      a[mi] = av;
    }

#pragma unroll
    for (int ni = 0; ni < 8; ++ni) {
      acc[0][ni] = __builtin_amdgcn_mfma_f32_16x16x32_bf16(a[0], bfr[ni], acc[0][ni], 0, 0, 0);
      acc[1][ni] = __builtin_amdgcn_mfma_f32_16x16x32_bf16(a[1], bfr[ni], acc[1][ni], 0, 0, 0);
    }
    __syncthreads();                       // protect buf[ks&1] before restage
  }

#pragma unroll
  for (int ni = 0; ni < 8; ++ni) {
    int col = ni * 16 + l15;
    float bj = bias[col];
#pragma unroll
    for (int mi = 0; mi < 2; ++mi) {
#pragma unroll
      for (int j = 0; j < 4; ++j) {
        int rr = bm + row0 + mi * 16 + l4 * 4 + j;
        if (rr < M) {
          float vv = acc[mi][ni][j] + bj;
          if (isU) {
            cu0b[(size_t)rr * HID + col] = f2bf(vv);
            if (rr >= NBOOKS) outu[(size_t)rr * HID + col] = vv * (1.0f / 3.0f);
          } else {
            outb[(size_t)rr * HID + col] = vv * (1.0f / 3.0f);
          }
        }
      }
    }
  }
}

// ---------------------------------------------------------------------------
__global__ void dis_kernel(const int* __restrict__ degu, const int* __restrict__ cntb,
                           float* __restrict__ dis)
{
  int i = blockIdx.x * blockDim.x + threadIdx.x;
  if (i < NUSERS) {
    int d = degu[i] + (i < NBOOKS ? cntb[i] : 0);
    dis[i] = (d > 0) ? rsqrtf((float)d) : 0.f;
  }
}

__global__ void fill_scatter(const int* __restrict__ rates, const int* __restrict__ impl,
                             const int* __restrict__ offs,
                             const unsigned int* __restrict__ relpos,
                             int* __restrict__ brow)
{
  int i = blockIdx.x * blockDim.x + threadIdx.x;
  if (i >= NEDGE) return;
  int u, bk;
  decode_edge(rates, impl, i, u, bk);
  brow[offs[bk] + (int)relpos[i]] = u;
}

// ---------------------------------------------------------------------------
__global__ __launch_bounds__(1024) void scan_blocks(const int* __restrict__ counts,
                                                    int* __restrict__ offs,
                                                    int* __restrict__ bsum, int N)
{
  __shared__ int buf[1024];
  int t = threadIdx.x;
  int i = blockIdx.x * 1024 + t;
  int v = (i < N) ? counts[i] : 0;
  buf[t] = v;
  __syncthreads();
  for (int off = 1; off < 1024; off <<= 1) {
    int x = (t >= off) ? buf[t - off] : 0;
    __syncthreads();
    buf[t] += x;
    __syncthreads();
  }
  int incl = buf[t];
  if (i < N) offs[i] = incl - v;
  if (t == 1023) bsum[blockIdx.x] = incl;
}

__global__ void scan_totals(const int* __restrict__ bsum, int* __restrict__ bpre,
                            int* __restrict__ offs, int nb, int N)
{
  if (threadIdx.x == 0 && blockIdx.x == 0) {
    int run = 0;
    for (int b = 0; b < nb; ++b) { bpre[b] = run; run += bsum[b]; }
    offs[N] = run;
  }
}

__global__ void add_prefix(int* __restrict__ offs, const int* __restrict__ bpre, int N)
{
  int i = blockIdx.x * blockDim.x + threadIdx.x;
  if (i < N) offs[i] += bpre[i >> 10];
}

// ---------------------------------------------------------------------------
// Pull layer 1: wave per dest, 4 lane-groups of 16, each group loads full
// 256B rows; 2x unroll = 8 rows in flight. shfl_xor(16|32) cross-group reduce.
// h1[c] = dis[c] * sum_u dis[u] * cu0[u].
// ---------------------------------------------------------------------------
__global__ __launch_bounds__(256) void pull1(const unsigned short* __restrict__ srcb,
    const int* __restrict__ offs, const int* __restrict__ brow,
    const float* __restrict__ dis, unsigned short* __restrict__ dstb)
{
  int c = (blockIdx.x << 2) + (threadIdx.x >> 6);
  if (c >= NBOOKS) return;
  const int lane = threadIdx.x & 63;
  const int g = lane >> 4, l = lane & 15;
  const int s = offs[c], e = offs[c + 1];

  float acc[8];
#pragma unroll
  for (int j = 0; j < 8; ++j) acc[j] = 0.f;

  int i = s + g;
  for (; i + 4 < e; i += 8) {
    int rr0 = brow[i], rr1 = brow[i + 4];
    float w0 = dis[rr0], w1 = dis[rr1];
    bf16x8 v0 = *reinterpret_cast<const bf16x8*>(&srcb[(size_t)rr0 * HID + l * 8]);
    bf16x8 v1 = *reinterpret_cast<const bf16x8*>(&srcb[(size_t)rr1 * HID + l * 8]);
#pragma unroll
    for (int j = 0; j < 8; ++j) acc[j] += w0 * bf2f((unsigned short)v0[j]);
#pragma unroll
    for (int j = 0; j < 8; ++j) acc[j] += w1 * bf2f((unsigned short)v1[j]);
  }
  if (i < e) {
    int rr = brow[i];
    float w = dis[rr];
    bf16x8 v = *reinterpret_cast<const bf16x8*>(&srcb[(size_t)rr * HID + l * 8]);
#pragma unroll
    for (int j = 0; j < 8; ++j) acc[j] += w * bf2f((unsigned short)v[j]);
  }

#pragma unroll
  for (int j = 0; j < 8; ++j) {
    acc[j] += __shfl_xor(acc[j], 16, 64);
    acc[j] += __shfl_xor(acc[j], 32, 64);
  }
  if (g == 0) {
    float db = dis[c];
    bf16x8 o;
#pragma unroll
    for (int j = 0; j < 8; ++j) o[j] = (short)f2bf(db * acc[j]);
    *reinterpret_cast<bf16x8*>(&dstb[(size_t)c * HID + l * 8]) = o;
  }
}

// Layer 2 + final mean (dests < NBOOKS). Branchless clamped gathers of h1b.
__global__ __launch_bounds__(256) void pull2_final(const unsigned short* __restrict__ h1b,
    const int* __restrict__ offs, const int* __restrict__ brow,
    const float* __restrict__ dis, const unsigned short* __restrict__ cu0b,
    float* __restrict__ outu)
{
  int c = (blockIdx.x << 2) + (threadIdx.x >> 6);
  if (c >= NBOOKS) return;
  const int lane = threadIdx.x & 63;
  const int g = lane >> 4, l = lane & 15;
  const int s = offs[c], e = offs[c + 1];

  float acc[8];
#pragma unroll
  for (int j = 0; j < 8; ++j) acc[j] = 0.f;

  int i = s + g;
  for (; i + 4 < e; i += 8) {
    int rr0 = brow[i], rr1 = brow[i + 4];
    int rc0 = rr0 < NBOOKS ? rr0 : 0;
    int rc1 = rr1 < NBOOKS ? rr1 : 0;
    float w0 = rr0 < NBOOKS ? dis[rr0] : 0.f;
    float w1 = rr1 < NBOOKS ? dis[rr1] : 0.f;
    bf16x8 v0 = *reinterpret_cast<const bf16x8*>(&h1b[(size_t)rc0 * HID + l * 8]);
    bf16x8 v1 = *reinterpret_cast<const bf16x8*>(&h1b[(size_t)rc1 * HID + l * 8]);
#pragma unroll
    for (int j = 0; j < 8; ++j) acc[j] += w0 * bf2f((unsigned short)v0[j]);
#pragma unroll
    for (int j = 0; j < 8; ++j) acc[j] += w1 * bf2f((unsigned short)v1[j]);
  }
  if (i < e) {
    int rr = brow[i];
    int rc = rr < NBOOKS ? rr : 0;
    float w = rr < NBOOKS ? dis[rr] : 0.f;
    bf16x8 v = *reinterpret_cast<const bf16x8*>(&h1b[(size_t)rc * HID + l * 8]);
#pragma unroll
    for (int j = 0; j < 8; ++j) acc[j] += w * bf2f((unsigned short)v[j]);
  }

#pragma unroll
  for (int j = 0; j < 8; ++j) {
    acc[j] += __shfl_xor(acc[j], 16, 64);
    acc[j] += __shfl_xor(acc[j], 32, 64);
  }
  if (g == 0) {
    float db = dis[c];
    size_t idx = (size_t)c * HID + l * 8;
    bf16x8 c0 = *reinterpret_cast<const bf16x8*>(&cu0b[idx]);
    bf16x8 h1 = *reinterpret_cast<const bf16x8*>(&h1b[idx]);
    float r[8];
#pragma unroll
    for (int j = 0; j < 8; ++j)
      r[j] = (bf2f((unsigned short)c0[j]) + bf2f((unsigned short)h1[j]) + db * acc[j]) * (1.0f / 3.0f);
    *reinterpret_cast<float4*>(&outu[idx])     = make_float4(r[0], r[1], r[2], r[3]);
    *reinterpret_cast<float4*>(&outu[idx + 4]) = make_float4(r[4], r[5], r[6], r[7]);
  }
}

// ---------------------------------------------------------------------------
extern "C" void kernel_launch(void* const* d_in, const int* in_sizes, int n_in,
                              void* d_out, int out_size, void* d_ws, size_t ws_size,
                              hipStream_t stream)
{
  const float* user_x = (const float*)d_in[0];
  const float* book_x = (const float*)d_in[1];
  const float* user_W = (const float*)d_in[2];
  const float* user_b = (const float*)d_in[3];
  const float* book_W = (const float*)d_in[4];
  const float* book_b = (const float*)d_in[5];
  const int*   rates  = (const int*)d_in[6];
  const int*   impl   = (const int*)d_in[7];

  float* out      = (float*)d_out;
  float* out_user = out;
  float* out_book = out + (size_t)NUSERS * HID;

  char* p = (char*)d_ws;
  auto carve = [&](size_t bytes) -> void* {
    void* r = (void*)p;
    p += (bytes + 255) & ~(size_t)255;
    return r;
  };
  unsigned short* cu0b   = (unsigned short*)carve((size_t)NUSERS * HID * 2);
  unsigned short* h1b    = (unsigned short*)carve((size_t)NBOOKS * HID * 2);
  unsigned short* wub    = (unsigned short*)carve((size_t)HID * FEAT * 2);
  unsigned short* wbb    = (unsigned short*)carve((size_t)HID * FEAT * 2);
  int*          degu   = (int*)carve((size_t)NUSERS * 4);
  int*          cntb   = (int*)carve((size_t)NBOOKS * 4);
  float*        dis    = (float*)carve((size_t)NUSERS * 4);
  int*          offs   = (int*)carve((size_t)(NBOOKS + 2) * 4);
  int*          bsum   = (int*)carve(256 * 4);
  int*          bpre   = (int*)carve(256 * 4);
  unsigned int* relpos = (unsigned int*)carve((size_t)NEDGE * 4);
  int*          brow   = (int*)carve((size_t)NEDGE * 4);

  hipMemsetAsync(degu, 0, (size_t)NUSERS * 4, stream);
  hipMemsetAsync(cntb, 0, (size_t)NBOOKS * 4, stream);

  cast_w<<<(HID * FEAT + 255) / 256, 256, 0, stream>>>(user_W, book_W, wub, wbb);

  // fused GEMM (LDS-staged MFMA) + edge histogram
  gemm_hist<<<GEMM_BLOCKS + HIST_BLOCKS, 256, 0, stream>>>(
      user_x, book_x, wub, wbb, user_b, book_b,
      cu0b, out_book, out_user, rates, impl, degu, cntb, relpos);

  dis_kernel<<<(NUSERS + 255) / 256, 256, 0, stream>>>(degu, cntb, dis);

  const int nb = (NBOOKS + 1023) / 1024;
  scan_blocks<<<nb, 1024, 0, stream>>>(cntb, offs, bsum, NBOOKS);
  scan_totals<<<1, 64, 0, stream>>>(bsum, bpre, offs, nb, NBOOKS);
  add_prefix<<<(NBOOKS + 255) / 256, 256, 0, stream>>>(offs, bpre, NBOOKS);
  fill_scatter<<<(NEDGE + 255) / 256, 256, 0, stream>>>(rates, impl, offs, relpos, brow);

  // propagation (dests < NBOOKS), layer 2 fuses final mean
  pull1<<<(NBOOKS + 3) / 4, 256, 0, stream>>>(cu0b, offs, brow, dis, h1b);
  pull2_final<<<(NBOOKS + 3) / 4, 256, 0, stream>>>(h1b, offs, brow, dis, cu0b, out_user);
}